// Round 12
// baseline (615.095 us; speedup 1.0000x reference)
//
#include <hip/hip_runtime.h>
#include <hip/hip_bf16.h>

#define N_NODES 50000
#define NIN 128
#define NOUT 64
#define EIN 32
#define N_EDGES 400000
#define N_UNITS (2 * N_EDGES)
#define ALPHA 0.2f
#define NBINS 16
#define NPB 32       // nodes per gather block
#define ECAP 1024    // LDS entry cache capacity (mean E=512, P(E>1024)~0)

__device__ __forceinline__ int clampi(int x) {
  return min(max(x, 0), N_NODES - 1);
}

__device__ __forceinline__ float bf2f(unsigned short u) {
  union { unsigned int i; float f; } v;
  v.i = ((unsigned int)u) << 16;
  return v.f;
}

// ---------------------------------------------------------------------------
// Kernel 1: h = node_fts @ W + b. Writes: out row first half (f32), bf16 copy
// hb (for the gather), fused A = h.a1, B = h.a2, hn = ||h||.
// ---------------------------------------------------------------------------
__global__ __launch_bounds__(256) void k_gemm(
    const float* __restrict__ nf, const float* __restrict__ W,
    const float* __restrict__ b, const float* __restrict__ a,
    __hip_bfloat16* __restrict__ hb, float* __restrict__ out,
    float* __restrict__ A, float* __restrict__ B, float* __restrict__ hn) {
  __shared__ float Ws[NIN * NOUT];  // 32 KB
  __shared__ float bs[NOUT], a1s[NOUT], a2s[NOUT];
  __shared__ float rows[4][NIN];
  int t = threadIdx.x;
#pragma unroll
  for (int n = 0; n < 32; ++n) Ws[t + n * 256] = W[t + n * 256];
  if (t < 64) { bs[t] = b[t]; a1s[t] = a[t]; a2s[t] = a[64 + t]; }
  __syncthreads();
  int j = t & 63, local = t >> 6;
  for (int v0 = blockIdx.x * 4; v0 < N_NODES; v0 += gridDim.x * 4) {
    int vload = v0 + (t >> 6);
    if (vload < N_NODES) {
      float2 p = ((const float2*)(nf + (size_t)vload * NIN))[t & 63];
      ((float2*)rows[t >> 6])[t & 63] = p;
    }
    __syncthreads();
    int v = v0 + local;
    if (v < N_NODES) {  // uniform per wave
      float acc = bs[j];
      const float* r = rows[local];
#pragma unroll
      for (int k = 0; k < NIN; k += 4) {
        float4 rk = *(const float4*)&r[k];
        acc += rk.x * Ws[(k + 0) * NOUT + j];
        acc += rk.y * Ws[(k + 1) * NOUT + j];
        acc += rk.z * Ws[(k + 2) * NOUT + j];
        acc += rk.w * Ws[(k + 3) * NOUT + j];
      }
      out[(size_t)v * 128 + j] = acc;  // output h-half directly
      hb[(size_t)v * NOUT + j] = __float2bfloat16(acc);
      float pa = acc * a1s[j], pb = acc * a2s[j], pn = acc * acc;
      for (int o = 32; o > 0; o >>= 1) {
        pa += __shfl_down(pa, o, 64);
        pb += __shfl_down(pb, o, 64);
        pn += __shfl_down(pn, o, 64);
      }
      if (j == 0) { A[v] = pa; B[v] = pb; hn[v] = sqrtf(pn); }
    }
    __syncthreads();
  }
}

// ---------------------------------------------------------------------------
// Kernel 2: per edge: lrelu logits both directions -> l[]; rank via count
// atomic. ef staged through padded LDS for coalesced global reads.
// ---------------------------------------------------------------------------
__global__ __launch_bounds__(256) void k_edge1(
    const int* __restrict__ eb, const float* __restrict__ ef,
    const float* __restrict__ a, const float* __restrict__ A,
    const float* __restrict__ B, float* __restrict__ l,
    int* __restrict__ rank, int* __restrict__ count) {
  __shared__ float efs[256][33];
  __shared__ float a3s[EIN];
  int t = threadIdx.x;
  if (t < EIN) a3s[t] = a[128 + t];
  int e0 = blockIdx.x * 256;
  int nrows = min(256, N_EDGES - e0);
  const float4* src = (const float4*)(ef + (size_t)e0 * EIN);
#pragma unroll
  for (int i = 0; i < 8; ++i) {
    int f = t + i * 256;
    int r = f >> 3, cg = (f & 7) * 4;
    if (r < nrows) {
      float4 v4 = src[f];
      efs[r][cg + 0] = v4.x;
      efs[r][cg + 1] = v4.y;
      efs[r][cg + 2] = v4.z;
      efs[r][cg + 3] = v4.w;
    }
  }
  __syncthreads();
  int i = e0 + t;
  if (i >= N_EDGES) return;
  float c = 0.f;
#pragma unroll
  for (int k = 0; k < EIN; ++k) c += efs[t][k] * a3s[k];
  int2 sd = ((const int2*)eb)[i];
  int s = clampi(sd.x), d = clampi(sd.y);
  float zf = A[s] + B[d] + c;  // forward: src=s, dst=d
  float zr = A[d] + B[s] + c;  // reverse: src=d, dst=s
  l[i] = zf > 0.f ? zf : ALPHA * zf;
  l[N_EDGES + i] = zr > 0.f ? zr : ALPHA * zr;
  rank[i] = atomicAdd(&count[s], 1);
  rank[N_EDGES + i] = atomicAdd(&count[d], 1);
}

// ---------------------------------------------------------------------------
// Kernel 3: single-block exclusive scan of count[50000] -> off.
// ---------------------------------------------------------------------------
__global__ __launch_bounds__(1024) void k_scan(const int* __restrict__ count,
                                               int* __restrict__ off) {
  __shared__ int ls[1024];
  int t = threadIdx.x;
  const int CH = 49;
  int start = t * CH, end = min(start + CH, N_NODES);
  int s = 0;
  for (int i = start; i < end; ++i) s += count[i];
  ls[t] = s;
  __syncthreads();
  for (int o = 1; o < 1024; o <<= 1) {
    int v = (t >= o) ? ls[t - o] : 0;
    __syncthreads();
    ls[t] += v;
    __syncthreads();
  }
  int run = (t == 0) ? 0 : ls[t - 1];
  for (int i = start; i < end; ++i) {
    off[i] = run;
    run += count[i];
  }
  if (t == 1023) off[N_NODES] = ls[1023];
}

// ---------------------------------------------------------------------------
// Kernel 4: pure scatter: csr[off[s]+rank[u]] = (dst, logit).
// ---------------------------------------------------------------------------
__global__ __launch_bounds__(256) void k_edge2(
    const int* __restrict__ eb, const float* __restrict__ l,
    const int* __restrict__ rank, const int* __restrict__ off,
    int2* __restrict__ csr) {
  int u = blockIdx.x * blockDim.x + threadIdx.x;
  if (u >= N_UNITS) return;
  int s, d;
  if (u < N_EDGES) {
    int2 sd = ((const int2*)eb)[u];
    s = sd.x; d = sd.y;
  } else {
    int2 sd = ((const int2*)eb)[u - N_EDGES];
    s = sd.y; d = sd.x;
  }
  s = clampi(s);
  d = clampi(d);
  csr[off[s] + rank[u]] = make_int2(d, __float_as_int(l[u]));
}

// ---------------------------------------------------------------------------
// Kernel 5: block-cooperative gather. One 256-thread block per 32 consecutive
// nodes (their CSR segments are contiguous).
//  A: stage the block's ~512 (dst,logit) entries into LDS (coalesced).
//  B: 32 threads: per-node sumexp -> lse, node id per entry, closed-form
//     variance terms (all from LDS, no global latency).
//  C: entry-parallel gather: lane (r=j>>4, g=j&15) loads ushort4 = cols
//     4g..4g+3 of entry e0+r(+4) -> one wave-load fetches 4 bf16 rows; 8
//     entries per wave-iter; accumulate via native LDS atomicAdd into
//     accs[n][c] with row stride 68 (bank-spread across r-groups, <=2-way).
//  D: wave w normalizes nodes w*8..w*8+7 (wave-uniform branches only!)
//     and stores the agg half coalesced. Variance -> binned f64 atomics.
// ---------------------------------------------------------------------------
__global__ __launch_bounds__(256) void k_gather(
    const __hip_bfloat16* __restrict__ hb, const float* __restrict__ hn,
    const int* __restrict__ off, const int2* __restrict__ csr,
    const float* __restrict__ scale_p, float* __restrict__ out,
    double* __restrict__ sums) {
  __shared__ int offs[NPB + 1];
  __shared__ int entries_d[ECAP];
  __shared__ float entries_l[ECAP];
  __shared__ unsigned char en[ECAP];
  __shared__ float lse_s[NPB];
  __shared__ float accs[NPB * 68];
  __shared__ double vs1[NPB], vs2[NPB];
  int t = threadIdx.x;
  int v0 = blockIdx.x * NPB;
  int nn = min(NPB, N_NODES - v0);
  if (t <= nn) offs[t] = off[v0 + t];
  for (int i = t; i < NPB * 68; i += 256) accs[i] = 0.f;
  __syncthreads();
  int base = offs[0];
  int E = offs[nn] - base;
  // ---- Phase A: stage entries ----
  int Ec = min(E, ECAP);
  for (int e = t; e < Ec; e += 256) {
    int2 ent = csr[base + e];
    entries_d[e] = ent.x;
    entries_l[e] = __int_as_float(ent.y);
  }
  __syncthreads();
  // ---- Phase B: per-node lse + variance (32 threads) ----
  double myS1 = 0.0, myS2 = 0.0;
  if (t < nn) {
    int e0 = offs[t] - base, e1 = offs[t + 1] - base;
    float sumexp = 0.f, sl = 0.f, sl2 = 0.f;
    for (int e = e0; e < e1; ++e) {
      float lv;
      if (e < ECAP) {
        lv = entries_l[e];
        en[e] = (unsigned char)t;
      } else {
        lv = __int_as_float(csr[base + e].y);
      }
      sumexp += expf(lv);
      sl += lv;
      sl2 += lv * lv;
    }
    int len = e1 - e0;
    float lse = logf(sumexp);  // len==0 -> -inf, but no entry references it
    lse_s[t] = lse;
    if (len > 0) {
      myS1 = (double)sl - (double)len * (double)lse;
      myS2 = (double)sl2 - 2.0 * (double)lse * (double)sl +
             (double)len * (double)lse * (double)lse;
    }
  }
  if (t < NPB) { vs1[t] = myS1; vs2[t] = myS2; }
  __syncthreads();
  // ---- Phase C: entry-parallel gather into LDS ----
  int lane = t & 63, w = t >> 6;
  int g = lane & 15, r = lane >> 4;
  const unsigned short* hus = (const unsigned short*)hb;
  for (int e0 = w * 8; e0 < E; e0 += 32) {
#pragma unroll
    for (int half = 0; half < 2; ++half) {
      int e = e0 + r + 4 * half;
      int d = 0, n = 0;
      float wt = 0.f;
      if (e < E) {
        if (e < ECAP) {
          d = entries_d[e];
          n = en[e];
          wt = entries_l[e] - lse_s[n];
        } else {  // overflow fallback (statistically never taken)
          int2 ent = csr[base + e];
          d = ent.x;
          int lo = 0, hi = nn - 1;
          while (lo < hi) {
            int mid = (lo + hi + 1) >> 1;
            if (offs[mid] - base <= e) lo = mid; else hi = mid - 1;
          }
          n = lo;
          wt = __int_as_float(ent.y) - lse_s[n];
        }
      }
      ushort4 u = *(const ushort4*)(hus + (size_t)d * NOUT + 4 * g);
      float* ac = &accs[n * 68 + 4 * g];
      atomicAdd(&ac[0], bf2f(u.x) * wt);
      atomicAdd(&ac[1], bf2f(u.y) * wt);
      atomicAdd(&ac[2], bf2f(u.z) * wt);
      atomicAdd(&ac[3], bf2f(u.w) * wt);
    }
  }
  __syncthreads();
  // ---- Phase D: normalize + store (wave-uniform control flow) ----
  float scale = scale_p[0];
#pragma unroll
  for (int i = 0; i < 8; ++i) {
    int n = w * 8 + i;
    if (n < nn) {  // uniform across the wave
      float m = accs[n * 68 + lane];
      float nr = m * m;
      for (int o = 32; o > 0; o >>= 1) nr += __shfl_xor(nr, o, 64);
      nr = sqrtf(nr);
      float fac = hn[v0 + n] * scale / fmaxf(nr, 1e-12f);
      out[(size_t)(v0 + n) * 128 + 64 + lane] = m * fac;
    }
  }
  if (t == 0) {
    double S1 = 0.0, S2 = 0.0;
#pragma unroll
    for (int i = 0; i < NPB; ++i) { S1 += vs1[i]; S2 += vs2[i]; }
    int bin = blockIdx.x & (NBINS - 1);
    atomicAdd(&sums[2 * bin], S1);
    atomicAdd(&sums[2 * bin + 1], S2);
  }
}

// ---------------------------------------------------------------------------
// Kernel 6: reduce 16 bins -> att_var -> out[6,400,000] (f32)
// ---------------------------------------------------------------------------
__global__ void k_var(const double* __restrict__ sums,
                      float* __restrict__ out) {
  if (threadIdx.x == 0 && blockIdx.x == 0) {
    double S1 = 0.0, S2 = 0.0;
#pragma unroll
    for (int i = 0; i < NBINS; ++i) {
      S1 += sums[2 * i];
      S2 += sums[2 * i + 1];
    }
    double M = (double)N_UNITS;
    double var = (S2 - S1 * S1 / M) / (M - 1.0);
    out[(size_t)N_NODES * 128] = (float)var;
  }
}

extern "C" void kernel_launch(void* const* d_in, const int* in_sizes, int n_in,
                              void* d_out, int out_size, void* d_ws,
                              size_t ws_size, hipStream_t stream) {
  const float* nf = (const float*)d_in[0];
  const float* ef = (const float*)d_in[1];
  const int* eb = (const int*)d_in[2];
  const float* W = (const float*)d_in[3];
  const float* b = (const float*)d_in[4];
  const float* a = (const float*)d_in[5];
  const float* scale_p = (const float*)d_in[6];
  float* out = (float*)d_out;  // 6,400,001 f32

  char* ws = (char*)d_ws;
  __hip_bfloat16* hb = (__hip_bfloat16*)(ws + 0);  //  6,400,000 B
  float* l = (float*)(ws + 6400000);               //  3,200,000 B
  int* rank = (int*)(ws + 9600000);                //  3,200,000 B
  int2* csr = (int2*)(ws + 12800000);              //  6,400,000 B
  float* A = (float*)(ws + 19200000);              //    200,000 B
  float* B = (float*)(ws + 19400000);              //    200,000 B
  float* hn = (float*)(ws + 19600000);             //    200,000 B
  int* off = (int*)(ws + 19800000);                //    200,016 B
  int* count = (int*)(ws + 20000016);              //    200,000 B
  double* sums = (double*)(ws + 20200016);         //        256 B

  hipMemsetAsync(ws + 20000016, 0, 200256, stream);  // count + sums

  k_gemm<<<1024, 256, 0, stream>>>(nf, W, b, a, hb, out, A, B, hn);
  k_edge1<<<(N_EDGES + 255) / 256, 256, 0, stream>>>(eb, ef, a, A, B, l, rank,
                                                     count);
  k_scan<<<1, 1024, 0, stream>>>(count, off);
  k_edge2<<<(N_UNITS + 255) / 256, 256, 0, stream>>>(eb, l, rank, off, csr);
  k_gather<<<(N_NODES + NPB - 1) / NPB, 256, 0, stream>>>(hb, hn, off, csr,
                                                          scale_p, out, sums);
  k_var<<<1, 64, 0, stream>>>(sums, out);
}